// Round 1
// 6056.331 us; speedup vs baseline: 1.0272x; 1.0272x over previous
//
#include <hip/hip_runtime.h>
#include <stdint.h>

// Problem constants (ModalityTransformer): B=32, T=1024, d=512, dff=2048, H=8, N=4, L=2
#define BST    32768              // B*T
#define NMOD   4
#define MTOT   (NMOD*BST)         // 131072 rows for all GEMMs
#define DMODEL 512
#define DFF    2048
#define NH     8
#define HDIM   64
#define NLAYER 2
#define LNEPS  1e-5f

using half8 = __attribute__((ext_vector_type(8))) _Float16;
using half4 = __attribute__((ext_vector_type(4))) _Float16;
using half2v = __attribute__((ext_vector_type(2))) _Float16;
using f32x4 = __attribute__((ext_vector_type(4))) float;

// async global -> LDS, 16B per lane. LDS dest is wave-uniform base + lane*16 (linear).
#define GLOAD_LDS16(g, l)                                                              \
    __builtin_amdgcn_global_load_lds((const __attribute__((address_space(1))) void*)(g), \
                                     (__attribute__((address_space(3))) void*)(l), 16, 0, 0)

// ---------------- fp32 -> fp16 convert (weights) ----------------
__global__ __launch_bounds__(256) void k_f32_to_f16(const float* __restrict__ src,
                                                    _Float16* __restrict__ dst, int n4) {
    int i = blockIdx.x * 256 + threadIdx.x;
    if (i >= n4) return;
    float4 v = ((const float4*)src)[i];
    half4 o = { (_Float16)v.x, (_Float16)v.y, (_Float16)v.z, (_Float16)v.w };
    ((half4*)dst)[i] = o;
}

// ---------------- concat 4x [BST, D] fp32 -> [4*BST, D] fp16 ----------------
__global__ __launch_bounds__(256) void k_concat4(const float* __restrict__ s0, const float* __restrict__ s1,
                                                 const float* __restrict__ s2, const float* __restrict__ s3,
                                                 _Float16* __restrict__ dst) {
    size_t i = (size_t)blockIdx.x * 256 + threadIdx.x;   // handles 4 elems
    size_t e = i * 4;
    int j = (int)(e >> 24);                              // BST*DMODEL = 2^24
    size_t rem = e & ((1u << 24) - 1);
    const float* s = (j == 0) ? s0 : (j == 1) ? s1 : (j == 2) ? s2 : s3;
    float4 v = *(const float4*)(s + rem);
    half4 o = { (_Float16)v.x, (_Float16)v.y, (_Float16)v.z, (_Float16)v.w };
    *(half4*)(dst + e) = o;
}

// ---------------- GEMM: C[M,F] = A[M,K] @ W[F,K]^T (+bias, opt ReLU), f16 in, f32 acc, f16 out
// m97 structure: 128x128 tile, BK=32, 256 threads (4 waves), global_load_lds(16B) staging,
// linear LDS, 2 barriers per K-step. Fragment layouts verified (learn_hip m89/m91):
// A-frag A[m=lane&15][k=quad*8+j]; B-frag B[k=quad*8+j][n=lane&15]; C/D: col=lane&15, row=quad*4+reg.
__global__ __launch_bounds__(256) void k_gemm_nt(const _Float16* __restrict__ A,
                                                 const _Float16* __restrict__ W,
                                                 const float* __restrict__ bias,
                                                 _Float16* __restrict__ C,
                                                 int K, int ldc, int relu) {
    __shared__ alignas(16) _Float16 As[128 * 32];
    __shared__ alignas(16) _Float16 Bs[128 * 32];
    const int tid  = threadIdx.x;
    const int lane = tid & 63;
    const int wv   = tid >> 6;        // 0..3
    const int quad = lane >> 4;       // 0..3
    const int lr   = lane & 15;
    const int wrow = (wv >> 1) * 64;
    const int wcol = (wv & 1) * 64;
    const size_t m0 = (size_t)blockIdx.x * 128;
    const size_t f0 = (size_t)blockIdx.y * 128;

    // staging geometry: one 16B chunk = 8 halves; tile = 128 rows x 4 chunks = 512 chunks.
    // Round r (r=0,1), wave w covers chunks [r*256 + w*64, +64); lane i takes chunk base+i.
    const int ch0  = wv * 64 + lane;        // 0..255
    const int ch1  = ch0 + 256;             // 256..511
    const int row0 = ch0 >> 2, c80 = (ch0 & 3) * 8;
    const int row1 = ch1 >> 2, c81 = (ch1 & 3) * 8;
    _Float16* As0 = As + (size_t)(wv * 64) * 8;          // wave-uniform LDS bases
    _Float16* As1 = As + (size_t)(256 + wv * 64) * 8;
    _Float16* Bs0 = Bs + (size_t)(wv * 64) * 8;
    _Float16* Bs1 = Bs + (size_t)(256 + wv * 64) * 8;
    const _Float16* Arow0 = A + (m0 + row0) * (size_t)K + c80;
    const _Float16* Arow1 = A + (m0 + row1) * (size_t)K + c81;
    const _Float16* Brow0 = W + (f0 + row0) * (size_t)K + c80;
    const _Float16* Brow1 = W + (f0 + row1) * (size_t)K + c81;

    f32x4 acc[4][4] = {};

    const int nk = K >> 5;
    for (int kt = 0; kt < nk; ++kt) {
        const int kof = kt << 5;
        GLOAD_LDS16(Arow0 + kof, As0);
        GLOAD_LDS16(Arow1 + kof, As1);
        GLOAD_LDS16(Brow0 + kof, Bs0);
        GLOAD_LDS16(Brow1 + kof, Bs1);
        __syncthreads();                      // drains vmcnt(0) -> data in LDS

        half8 af[4], bf[4];
#pragma unroll
        for (int mt = 0; mt < 4; ++mt)
            af[mt] = *(const half8*)(As + (wrow + mt * 16 + lr) * 32 + quad * 8);
#pragma unroll
        for (int nt = 0; nt < 4; ++nt)
            bf[nt] = *(const half8*)(Bs + (wcol + nt * 16 + lr) * 32 + quad * 8);
#pragma unroll
        for (int mt = 0; mt < 4; ++mt)
#pragma unroll
            for (int nt = 0; nt < 4; ++nt)
                acc[mt][nt] = __builtin_amdgcn_mfma_f32_16x16x32_f16(af[mt], bf[nt], acc[mt][nt], 0, 0, 0);
        __syncthreads();                      // protect LDS before next overwrite
    }

#pragma unroll
    for (int nt = 0; nt < 4; ++nt) {
        const int col = (int)f0 + wcol + nt * 16 + lr;
        const float bv = bias ? bias[col] : 0.0f;
#pragma unroll
        for (int mt = 0; mt < 4; ++mt) {
#pragma unroll
            for (int r = 0; r < 4; ++r) {
                size_t row = m0 + wrow + mt * 16 + quad * 4 + r;
                float v = acc[mt][nt][r] + bv;
                if (relu) v = v > 0.0f ? v : 0.0f;
                C[row * (size_t)ldc + col] = (_Float16)v;
            }
        }
    }
}

// ---------------- attention core: per (bs): softmax(causal 4x4 scores) @ V, all 8 heads ----------------
// grid = BST blocks x 256; wave w handles heads 2w,2w+1: lanes 0-31 -> head 2w, 32-63 -> head 2w+1;
// each lane holds 2 contiguous hd elems (half2 loads, fully coalesced 256B/wave per row).
__global__ __launch_bounds__(256) void k_attn(const _Float16* __restrict__ Q,
                                              const _Float16* __restrict__ Kp,
                                              const _Float16* __restrict__ Vp,
                                              int ldq, _Float16* __restrict__ O, int ldo) {
    const int bs = blockIdx.x;
    const int tid = threadIdx.x;
    const int w = tid >> 6;
    const int c = tid & 63;
    const int h = (w << 1) + (c >> 5);     // head 0..7
    const int e = (c & 31) << 1;           // hd elem pair base
    float qx[4], qy[4], kx[4], ky[4], vx[4], vy[4];
#pragma unroll
    for (int i = 0; i < 4; ++i) {
        size_t off = ((size_t)(i * BST + bs)) * ldq + h * 64 + e;
        half2v qq = *(const half2v*)(Q + off);
        half2v kk = *(const half2v*)(Kp + off);
        half2v vv = *(const half2v*)(Vp + off);
        qx[i] = (float)qq.x; qy[i] = (float)qq.y;
        kx[i] = (float)kk.x; ky[i] = (float)kk.y;
        vx[i] = (float)vv.x; vy[i] = (float)vv.y;
    }
    float s[4][4];
#pragma unroll
    for (int i = 0; i < 4; ++i)
#pragma unroll
        for (int j = 0; j < 4; ++j) {
            if (j > i) continue;
            float p = qx[i] * kx[j] + qy[i] * ky[j];
#pragma unroll
            for (int off = 16; off >= 1; off >>= 1) p += __shfl_xor(p, off, 64);
            s[i][j] = p * 0.125f;   // 1/sqrt(64)
        }
#pragma unroll
    for (int i = 0; i < 4; ++i) {
        float mx = s[i][0];
        for (int j = 1; j <= i; ++j) mx = fmaxf(mx, s[i][j]);
        float ee[4], sum = 0.0f;
        for (int j = 0; j <= i; ++j) { ee[j] = __expf(s[i][j] - mx); sum += ee[j]; }
        float inv = 1.0f / sum;
        float ox = 0.0f, oy = 0.0f;
        for (int j = 0; j <= i; ++j) { ox += ee[j] * vx[j]; oy += ee[j] * vy[j]; }
        half2v o = { (_Float16)(ox * inv), (_Float16)(oy * inv) };
        *(half2v*)(O + ((size_t)(i * BST + bs)) * ldo + h * 64 + e) = o;
    }
}

// ---------------- add + LayerNorm (row = 512). wave per row; lane c holds halves [8c, 8c+8) ----------------
__global__ __launch_bounds__(256) void k_add_ln(const _Float16* __restrict__ X,
                                                const _Float16* __restrict__ Y,
                                                const float* __restrict__ g,
                                                const float* __restrict__ b,
                                                _Float16* __restrict__ out16,
                                                float* __restrict__ out32) {
    const int tid = threadIdx.x;
    const int w = tid >> 6, c = tid & 63;
    const size_t m = (size_t)blockIdx.x * 4 + w;
    const size_t base = m * DMODEL + (size_t)c * 8;
    half8 xv = *(const half8*)(X + base);
    half8 yv = *(const half8*)(Y + base);
    float v[8];
    float sum = 0.0f;
#pragma unroll
    for (int e = 0; e < 8; ++e) { v[e] = (float)xv[e] + (float)yv[e]; sum += v[e]; }
#pragma unroll
    for (int off = 32; off >= 1; off >>= 1) sum += __shfl_xor(sum, off, 64);
    const float mu = sum * (1.0f / 512.0f);
    float vs = 0.0f;
#pragma unroll
    for (int e = 0; e < 8; ++e) { float d = v[e] - mu; vs += d * d; }
#pragma unroll
    for (int off = 32; off >= 1; off >>= 1) vs += __shfl_xor(vs, off, 64);
    const float rs = rsqrtf(vs * (1.0f / 512.0f) + LNEPS);
    float gv[8], bv[8];
    *(float4*)(gv)     = *(const float4*)(g + c * 8);
    *(float4*)(gv + 4) = *(const float4*)(g + c * 8 + 4);
    *(float4*)(bv)     = *(const float4*)(b + c * 8);
    *(float4*)(bv + 4) = *(const float4*)(b + c * 8 + 4);
    if (out32) {
        float o[8];
#pragma unroll
        for (int e = 0; e < 8; ++e) o[e] = (v[e] - mu) * rs * gv[e] + bv[e];
        *(float4*)(out32 + base)     = *(float4*)(o);
        *(float4*)(out32 + base + 4) = *(float4*)(o + 4);
    } else {
        half8 o;
#pragma unroll
        for (int e = 0; e < 8; ++e) o[e] = (_Float16)((v[e] - mu) * rs * gv[e] + bv[e]);
        *(half8*)(out16 + base) = o;
    }
}

extern "C" void kernel_launch(void* const* d_in, const int* in_sizes, int n_in,
                              void* d_out, int out_size, void* d_ws, size_t ws_size,
                              hipStream_t stream) {
    const float* ctx0       = (const float*)d_in[0];
    const float* ctx1       = (const float*)d_in[1];
    const float* ctx2       = (const float*)d_in[2];
    const float* h_ctx      = (const float*)d_in[3];
    const float* h_tgt0     = (const float*)d_in[4];
    const float* h_tgt1     = (const float*)d_in[5];
    const float* h_tgt2     = (const float*)d_in[6];
    const float* h_tgt3     = (const float*)d_in[7];
    const float* Wqkv_self  = (const float*)d_in[8];
    const float* bqkv_self  = (const float*)d_in[9];
    const float* Wo_self    = (const float*)d_in[10];
    const float* bo_self    = (const float*)d_in[11];
    const float* Wqkv_cross = (const float*)d_in[12];
    const float* bqkv_cross = (const float*)d_in[13];
    const float* Wo_cross   = (const float*)d_in[14];
    const float* bo_cross   = (const float*)d_in[15];
    const float* W1         = (const float*)d_in[16];
    const float* b1         = (const float*)d_in[17];
    const float* W2         = (const float*)d_in[18];
    const float* b2         = (const float*)d_in[19];
    const float* ln_g       = (const float*)d_in[20];
    const float* ln_b       = (const float*)d_in[21];

    char* wsb = (char*)d_ws;
    size_t off = 0;
    auto carve = [&](size_t bytes) -> void* {
        void* p = wsb + off;
        off += (bytes + 255) & ~(size_t)255;
        return p;
    };
    _Float16* x     = (_Float16*)carve((size_t)MTOT * DMODEL * 2);
    _Float16* memb  = (_Float16*)carve((size_t)MTOT * DMODEL * 2);
    _Float16* big   = (_Float16*)carve((size_t)MTOT * DFF * 2);     // qkv (M x 1536) + attno (M x 512)
    _Float16* projo = (_Float16*)carve((size_t)MTOT * DMODEL * 2);
    _Float16* wqs = (_Float16*)carve((size_t)NLAYER * 3 * DMODEL * DMODEL * 2);
    _Float16* wos = (_Float16*)carve((size_t)NLAYER * DMODEL * DMODEL * 2);
    _Float16* wqc = (_Float16*)carve((size_t)NLAYER * 3 * DMODEL * DMODEL * 2);
    _Float16* woc = (_Float16*)carve((size_t)NLAYER * DMODEL * DMODEL * 2);
    _Float16* w1h = (_Float16*)carve((size_t)NLAYER * DFF * DMODEL * 2);
    _Float16* w2h = (_Float16*)carve((size_t)NLAYER * DMODEL * DFF * 2);
    _Float16* attno = big + (size_t)MTOT * 1536;

    auto conv = [&](const float* s, _Float16* dst, int n) {
        int n4 = n / 4;
        k_f32_to_f16<<<(n4 + 255) / 256, 256, 0, stream>>>(s, dst, n4);
    };
    conv(Wqkv_self,  wqs, NLAYER * 3 * DMODEL * DMODEL);
    conv(Wo_self,    wos, NLAYER * DMODEL * DMODEL);
    conv(Wqkv_cross, wqc, NLAYER * 3 * DMODEL * DMODEL);
    conv(Wo_cross,   woc, NLAYER * DMODEL * DMODEL);
    conv(W1,         w1h, NLAYER * DFF * DMODEL);
    conv(W2,         w2h, NLAYER * DMODEL * DFF);

    const int concat_blocks = (MTOT * DMODEL / 4) / 256;   // 65536
    k_concat4<<<concat_blocks, 256, 0, stream>>>(h_tgt0, h_tgt1, h_tgt2, h_tgt3, x);
    k_concat4<<<concat_blocks, 256, 0, stream>>>(h_ctx, ctx0, ctx1, ctx2, memb);

    auto gemm = [&](const _Float16* A, const _Float16* Wp, const float* bias, _Float16* Cc,
                    int K, int F, int ldc, int relu) {
        dim3 g(MTOT / 128, F / 128);
        k_gemm_nt<<<g, 256, 0, stream>>>(A, Wp, bias, Cc, K, ldc, relu);
    };

    for (int l = 0; l < NLAYER; ++l) {
        // ---- self attention ----
        gemm(x, wqs + (size_t)l * 3 * DMODEL * DMODEL, bqkv_self + l * 3 * DMODEL,
             big, DMODEL, 3 * DMODEL, 3 * DMODEL, 0);
        k_attn<<<BST, 256, 0, stream>>>(big, big + 512, big + 1024, 3 * DMODEL, attno, DMODEL);
        gemm(attno, wos + (size_t)l * DMODEL * DMODEL, bo_self + l * DMODEL,
             projo, DMODEL, DMODEL, DMODEL, 0);
        k_add_ln<<<MTOT / 4, 256, 0, stream>>>(x, projo, ln_g + (l * 3 + 0) * DMODEL,
                                               ln_b + (l * 3 + 0) * DMODEL, x, nullptr);
        // ---- cross attention ----
        const _Float16* Wc = wqc + (size_t)l * 3 * DMODEL * DMODEL;
        gemm(x, Wc, bqkv_cross + l * 3 * DMODEL, big, DMODEL, DMODEL, 3 * DMODEL, 0);          // Q
        gemm(memb, Wc + (size_t)DMODEL * DMODEL, bqkv_cross + l * 3 * DMODEL + DMODEL,
             big + 512, DMODEL, 2 * DMODEL, 3 * DMODEL, 0);                                     // K,V
        k_attn<<<BST, 256, 0, stream>>>(big, big + 512, big + 1024, 3 * DMODEL, attno, DMODEL);
        gemm(attno, woc + (size_t)l * DMODEL * DMODEL, bo_cross + l * DMODEL,
             projo, DMODEL, DMODEL, DMODEL, 0);
        k_add_ln<<<MTOT / 4, 256, 0, stream>>>(x, projo, ln_g + (l * 3 + 1) * DMODEL,
                                               ln_b + (l * 3 + 1) * DMODEL, x, nullptr);
        // ---- FFN ----
        gemm(x, w1h + (size_t)l * DFF * DMODEL, b1 + l * DFF, big, DMODEL, DFF, DFF, 1);
        gemm(big, w2h + (size_t)l * DMODEL * DFF, b2 + l * DMODEL, projo, DFF, DMODEL, DMODEL, 0);
        const bool last = (l == NLAYER - 1);
        k_add_ln<<<MTOT / 4, 256, 0, stream>>>(x, projo, ln_g + (l * 3 + 2) * DMODEL,
                                               ln_b + (l * 3 + 2) * DMODEL,
                                               last ? nullptr : x, last ? (float*)d_out : nullptr);
    }
    (void)in_sizes; (void)n_in; (void)out_size; (void)ws_size;
}

// Round 2
// 5284.535 us; speedup vs baseline: 1.1772x; 1.1460x over previous
//
#include <hip/hip_runtime.h>
#include <stdint.h>

// Problem constants (ModalityTransformer): B=32, T=1024, d=512, dff=2048, H=8, N=4, L=2
#define BST    32768              // B*T
#define NMOD   4
#define MTOT   (NMOD*BST)         // 131072 rows for all GEMMs
#define DMODEL 512
#define DFF    2048
#define NH     8
#define HDIM   64
#define NLAYER 2
#define LNEPS  1e-5f

using half8 = __attribute__((ext_vector_type(8))) _Float16;
using half4 = __attribute__((ext_vector_type(4))) _Float16;
using half2v = __attribute__((ext_vector_type(2))) _Float16;
using f32x4 = __attribute__((ext_vector_type(4))) float;

// async global -> LDS, 16B per lane. LDS dest is wave-uniform base + lane*16 (linear).
#define GLOAD_LDS16(g, l)                                                              \
    __builtin_amdgcn_global_load_lds((const __attribute__((address_space(1))) void*)(g), \
                                     (__attribute__((address_space(3))) void*)(l), 16, 0, 0)

// ---------------- fp32 -> fp16 convert (weights) ----------------
__global__ __launch_bounds__(256) void k_f32_to_f16(const float* __restrict__ src,
                                                    _Float16* __restrict__ dst, int n4) {
    int i = blockIdx.x * 256 + threadIdx.x;
    if (i >= n4) return;
    float4 v = ((const float4*)src)[i];
    half4 o = { (_Float16)v.x, (_Float16)v.y, (_Float16)v.z, (_Float16)v.w };
    ((half4*)dst)[i] = o;
}

// ---------------- concat 4x [BST, D] fp32 -> [4*BST, D] fp16 ----------------
__global__ __launch_bounds__(256) void k_concat4(const float* __restrict__ s0, const float* __restrict__ s1,
                                                 const float* __restrict__ s2, const float* __restrict__ s3,
                                                 _Float16* __restrict__ dst) {
    size_t i = (size_t)blockIdx.x * 256 + threadIdx.x;   // handles 4 elems
    size_t e = i * 4;
    int j = (int)(e >> 24);                              // BST*DMODEL = 2^24
    size_t rem = e & ((1u << 24) - 1);
    const float* s = (j == 0) ? s0 : (j == 1) ? s1 : (j == 2) ? s2 : s3;
    float4 v = *(const float4*)(s + rem);
    half4 o = { (_Float16)v.x, (_Float16)v.y, (_Float16)v.z, (_Float16)v.w };
    *(half4*)(dst + e) = o;
}

// ---------------- GEMM: C[M,F] = A[M,K] @ W[F,K]^T (+bias, opt ReLU), f16 in, f32 acc, f16 out
// m97 structure: 128x128 tile, BK=32, 256 threads (4 waves), global_load_lds(16B) staging,
// linear LDS, 2 barriers per K-step.
// Grid is 1D; block id is remapped (T1 XCD-chunk swizzle, bijective since nwg%8==0) so each
// XCD owns a contiguous run of M-panels and iterates the nf F-blocks of a panel fastest:
// A-tile is fetched once into that XCD's L2 and reused nf times; W (<=2MB) stays L2-resident.
__global__ __launch_bounds__(256) void k_gemm_nt(const _Float16* __restrict__ A,
                                                 const _Float16* __restrict__ W,
                                                 const float* __restrict__ bias,
                                                 _Float16* __restrict__ C,
                                                 int K, int ldc, int relu, int nf) {
    __shared__ alignas(16) _Float16 As[128 * 32];
    __shared__ alignas(16) _Float16 Bs[128 * 32];
    const int tid  = threadIdx.x;
    const int lane = tid & 63;
    const int wv   = tid >> 6;        // 0..3
    const int quad = lane >> 4;       // 0..3
    const int lr   = lane & 15;
    const int wrow = (wv >> 1) * 64;
    const int wcol = (wv & 1) * 64;

    // XCD-chunk swizzle + F-fastest decomposition
    const int nwg = gridDim.x;                       // = (M/128)*nf, divisible by 8
    int bid = blockIdx.x;
    bid = (bid & 7) * (nwg >> 3) + (bid >> 3);
    const int fblk = bid % nf;
    const int mblk = bid / nf;
    const size_t m0 = (size_t)mblk * 128;
    const size_t f0 = (size_t)fblk * 128;

    // staging geometry: one 16B chunk = 8 halves; tile = 128 rows x 4 chunks = 512 chunks.
    const int ch0  = wv * 64 + lane;        // 0..255
    const int ch1  = ch0 + 256;             // 256..511
    const int row0 = ch0 >> 2, c80 = (ch0 & 3) * 8;
    const int row1 = ch1 >> 2, c81 = (ch1 & 3) * 8;
    _Float16* As0 = As + (size_t)(wv * 64) * 8;          // wave-uniform LDS bases
    _Float16* As1 = As + (size_t)(256 + wv * 64) * 8;
    _Float16* Bs0 = Bs + (size_t)(wv * 64) * 8;
    _Float16* Bs1 = Bs + (size_t)(256 + wv * 64) * 8;
    const _Float16* Arow0 = A + (m0 + row0) * (size_t)K + c80;
    const _Float16* Arow1 = A + (m0 + row1) * (size_t)K + c81;
    const _Float16* Brow0 = W + (f0 + row0) * (size_t)K + c80;
    const _Float16* Brow1 = W + (f0 + row1) * (size_t)K + c81;

    f32x4 acc[4][4] = {};

    const int nk = K >> 5;
    for (int kt = 0; kt < nk; ++kt) {
        const int kof = kt << 5;
        GLOAD_LDS16(Arow0 + kof, As0);
        GLOAD_LDS16(Arow1 + kof, As1);
        GLOAD_LDS16(Brow0 + kof, Bs0);
        GLOAD_LDS16(Brow1 + kof, Bs1);
        __syncthreads();                      // drains vmcnt(0) -> data in LDS

        half8 af[4], bf[4];
#pragma unroll
        for (int mt = 0; mt < 4; ++mt)
            af[mt] = *(const half8*)(As + (wrow + mt * 16 + lr) * 32 + quad * 8);
#pragma unroll
        for (int nt = 0; nt < 4; ++nt)
            bf[nt] = *(const half8*)(Bs + (wcol + nt * 16 + lr) * 32 + quad * 8);
#pragma unroll
        for (int mt = 0; mt < 4; ++mt)
#pragma unroll
            for (int nt = 0; nt < 4; ++nt)
                acc[mt][nt] = __builtin_amdgcn_mfma_f32_16x16x32_f16(af[mt], bf[nt], acc[mt][nt], 0, 0, 0);
        __syncthreads();                      // protect LDS before next overwrite
    }

#pragma unroll
    for (int nt = 0; nt < 4; ++nt) {
        const int col = (int)f0 + wcol + nt * 16 + lr;
        const float bv = bias ? bias[col] : 0.0f;
#pragma unroll
        for (int mt = 0; mt < 4; ++mt) {
#pragma unroll
            for (int r = 0; r < 4; ++r) {
                size_t row = m0 + wrow + mt * 16 + quad * 4 + r;
                float v = acc[mt][nt][r] + bv;
                if (relu) v = v > 0.0f ? v : 0.0f;
                C[row * (size_t)ldc + col] = (_Float16)v;
            }
        }
    }
}

// ---------------- attention core: per (bs): softmax(causal 4x4 scores) @ V, all 8 heads ----------------
__global__ __launch_bounds__(256) void k_attn(const _Float16* __restrict__ Q,
                                              const _Float16* __restrict__ Kp,
                                              const _Float16* __restrict__ Vp,
                                              int ldq, _Float16* __restrict__ O, int ldo) {
    const int bs = blockIdx.x;
    const int tid = threadIdx.x;
    const int w = tid >> 6;
    const int c = tid & 63;
    const int h = (w << 1) + (c >> 5);     // head 0..7
    const int e = (c & 31) << 1;           // hd elem pair base
    float qx[4], qy[4], kx[4], ky[4], vx[4], vy[4];
#pragma unroll
    for (int i = 0; i < 4; ++i) {
        size_t off = ((size_t)(i * BST + bs)) * ldq + h * 64 + e;
        half2v qq = *(const half2v*)(Q + off);
        half2v kk = *(const half2v*)(Kp + off);
        half2v vv = *(const half2v*)(Vp + off);
        qx[i] = (float)qq.x; qy[i] = (float)qq.y;
        kx[i] = (float)kk.x; ky[i] = (float)kk.y;
        vx[i] = (float)vv.x; vy[i] = (float)vv.y;
    }
    float s[4][4];
#pragma unroll
    for (int i = 0; i < 4; ++i)
#pragma unroll
        for (int j = 0; j < 4; ++j) {
            if (j > i) continue;
            float p = qx[i] * kx[j] + qy[i] * ky[j];
#pragma unroll
            for (int off = 16; off >= 1; off >>= 1) p += __shfl_xor(p, off, 64);
            s[i][j] = p * 0.125f;   // 1/sqrt(64)
        }
#pragma unroll
    for (int i = 0; i < 4; ++i) {
        float mx = s[i][0];
        for (int j = 1; j <= i; ++j) mx = fmaxf(mx, s[i][j]);
        float ee[4], sum = 0.0f;
        for (int j = 0; j <= i; ++j) { ee[j] = __expf(s[i][j] - mx); sum += ee[j]; }
        float inv = 1.0f / sum;
        float ox = 0.0f, oy = 0.0f;
        for (int j = 0; j <= i; ++j) { ox += ee[j] * vx[j]; oy += ee[j] * vy[j]; }
        half2v o = { (_Float16)(ox * inv), (_Float16)(oy * inv) };
        *(half2v*)(O + ((size_t)(i * BST + bs)) * ldo + h * 64 + e) = o;
    }
}

// ---------------- add + LayerNorm (row = 512). wave per row; lane c holds halves [8c, 8c+8) ----------------
__global__ __launch_bounds__(256) void k_add_ln(const _Float16* __restrict__ X,
                                                const _Float16* __restrict__ Y,
                                                const float* __restrict__ g,
                                                const float* __restrict__ b,
                                                _Float16* __restrict__ out16,
                                                float* __restrict__ out32) {
    const int tid = threadIdx.x;
    const int w = tid >> 6, c = tid & 63;
    const size_t m = (size_t)blockIdx.x * 4 + w;
    const size_t base = m * DMODEL + (size_t)c * 8;
    half8 xv = *(const half8*)(X + base);
    half8 yv = *(const half8*)(Y + base);
    float v[8];
    float sum = 0.0f;
#pragma unroll
    for (int e = 0; e < 8; ++e) { v[e] = (float)xv[e] + (float)yv[e]; sum += v[e]; }
#pragma unroll
    for (int off = 32; off >= 1; off >>= 1) sum += __shfl_xor(sum, off, 64);
    const float mu = sum * (1.0f / 512.0f);
    float vs = 0.0f;
#pragma unroll
    for (int e = 0; e < 8; ++e) { float d = v[e] - mu; vs += d * d; }
#pragma unroll
    for (int off = 32; off >= 1; off >>= 1) vs += __shfl_xor(vs, off, 64);
    const float rs = rsqrtf(vs * (1.0f / 512.0f) + LNEPS);
    float gv[8], bv[8];
    *(float4*)(gv)     = *(const float4*)(g + c * 8);
    *(float4*)(gv + 4) = *(const float4*)(g + c * 8 + 4);
    *(float4*)(bv)     = *(const float4*)(b + c * 8);
    *(float4*)(bv + 4) = *(const float4*)(b + c * 8 + 4);
    if (out32) {
        float o[8];
#pragma unroll
        for (int e = 0; e < 8; ++e) o[e] = (v[e] - mu) * rs * gv[e] + bv[e];
        *(float4*)(out32 + base)     = *(float4*)(o);
        *(float4*)(out32 + base + 4) = *(float4*)(o + 4);
    } else {
        half8 o;
#pragma unroll
        for (int e = 0; e < 8; ++e) o[e] = (_Float16)((v[e] - mu) * rs * gv[e] + bv[e]);
        *(half8*)(out16 + base) = o;
    }
}

extern "C" void kernel_launch(void* const* d_in, const int* in_sizes, int n_in,
                              void* d_out, int out_size, void* d_ws, size_t ws_size,
                              hipStream_t stream) {
    const float* ctx0       = (const float*)d_in[0];
    const float* ctx1       = (const float*)d_in[1];
    const float* ctx2       = (const float*)d_in[2];
    const float* h_ctx      = (const float*)d_in[3];
    const float* h_tgt0     = (const float*)d_in[4];
    const float* h_tgt1     = (const float*)d_in[5];
    const float* h_tgt2     = (const float*)d_in[6];
    const float* h_tgt3     = (const float*)d_in[7];
    const float* Wqkv_self  = (const float*)d_in[8];
    const float* bqkv_self  = (const float*)d_in[9];
    const float* Wo_self    = (const float*)d_in[10];
    const float* bo_self    = (const float*)d_in[11];
    const float* Wqkv_cross = (const float*)d_in[12];
    const float* bqkv_cross = (const float*)d_in[13];
    const float* Wo_cross   = (const float*)d_in[14];
    const float* bo_cross   = (const float*)d_in[15];
    const float* W1         = (const float*)d_in[16];
    const float* b1         = (const float*)d_in[17];
    const float* W2         = (const float*)d_in[18];
    const float* b2         = (const float*)d_in[19];
    const float* ln_g       = (const float*)d_in[20];
    const float* ln_b       = (const float*)d_in[21];

    char* wsb = (char*)d_ws;
    size_t off = 0;
    auto carve = [&](size_t bytes) -> void* {
        void* p = wsb + off;
        off += (bytes + 255) & ~(size_t)255;
        return p;
    };
    _Float16* x     = (_Float16*)carve((size_t)MTOT * DMODEL * 2);
    _Float16* memb  = (_Float16*)carve((size_t)MTOT * DMODEL * 2);
    _Float16* big   = (_Float16*)carve((size_t)MTOT * DFF * 2);     // qkv (M x 1536) + attno (M x 512)
    _Float16* projo = (_Float16*)carve((size_t)MTOT * DMODEL * 2);
    _Float16* wqs = (_Float16*)carve((size_t)NLAYER * 3 * DMODEL * DMODEL * 2);
    _Float16* wos = (_Float16*)carve((size_t)NLAYER * DMODEL * DMODEL * 2);
    _Float16* wqc = (_Float16*)carve((size_t)NLAYER * 3 * DMODEL * DMODEL * 2);
    _Float16* woc = (_Float16*)carve((size_t)NLAYER * DMODEL * DMODEL * 2);
    _Float16* w1h = (_Float16*)carve((size_t)NLAYER * DFF * DMODEL * 2);
    _Float16* w2h = (_Float16*)carve((size_t)NLAYER * DMODEL * DFF * 2);
    _Float16* attno = big + (size_t)MTOT * 1536;

    auto conv = [&](const float* s, _Float16* dst, int n) {
        int n4 = n / 4;
        k_f32_to_f16<<<(n4 + 255) / 256, 256, 0, stream>>>(s, dst, n4);
    };
    conv(Wqkv_self,  wqs, NLAYER * 3 * DMODEL * DMODEL);
    conv(Wo_self,    wos, NLAYER * DMODEL * DMODEL);
    conv(Wqkv_cross, wqc, NLAYER * 3 * DMODEL * DMODEL);
    conv(Wo_cross,   woc, NLAYER * DMODEL * DMODEL);
    conv(W1,         w1h, NLAYER * DFF * DMODEL);
    conv(W2,         w2h, NLAYER * DMODEL * DFF);

    const int concat_blocks = (MTOT * DMODEL / 4) / 256;   // 65536
    k_concat4<<<concat_blocks, 256, 0, stream>>>(h_tgt0, h_tgt1, h_tgt2, h_tgt3, x);
    k_concat4<<<concat_blocks, 256, 0, stream>>>(h_ctx, ctx0, ctx1, ctx2, memb);

    auto gemm = [&](const _Float16* A, const _Float16* Wp, const float* bias, _Float16* Cc,
                    int K, int F, int ldc, int relu) {
        int nf = F / 128;
        int nwg = (MTOT / 128) * nf;
        k_gemm_nt<<<nwg, 256, 0, stream>>>(A, Wp, bias, Cc, K, ldc, relu, nf);
    };

    for (int l = 0; l < NLAYER; ++l) {
        // ---- self attention ----
        gemm(x, wqs + (size_t)l * 3 * DMODEL * DMODEL, bqkv_self + l * 3 * DMODEL,
             big, DMODEL, 3 * DMODEL, 3 * DMODEL, 0);
        k_attn<<<BST, 256, 0, stream>>>(big, big + 512, big + 1024, 3 * DMODEL, attno, DMODEL);
        gemm(attno, wos + (size_t)l * DMODEL * DMODEL, bo_self + l * DMODEL,
             projo, DMODEL, DMODEL, DMODEL, 0);
        k_add_ln<<<MTOT / 4, 256, 0, stream>>>(x, projo, ln_g + (l * 3 + 0) * DMODEL,
                                               ln_b + (l * 3 + 0) * DMODEL, x, nullptr);
        // ---- cross attention ----
        const _Float16* Wc = wqc + (size_t)l * 3 * DMODEL * DMODEL;
        gemm(x, Wc, bqkv_cross + l * 3 * DMODEL, big, DMODEL, DMODEL, 3 * DMODEL, 0);          // Q
        gemm(memb, Wc + (size_t)DMODEL * DMODEL, bqkv_cross + l * 3 * DMODEL + DMODEL,
             big + 512, DMODEL, 2 * DMODEL, 3 * DMODEL, 0);                                     // K,V
        k_attn<<<BST, 256, 0, stream>>>(big, big + 512, big + 1024, 3 * DMODEL, attno, DMODEL);
        gemm(attno, woc + (size_t)l * DMODEL * DMODEL, bo_cross + l * DMODEL,
             projo, DMODEL, DMODEL, DMODEL, 0);
        k_add_ln<<<MTOT / 4, 256, 0, stream>>>(x, projo, ln_g + (l * 3 + 1) * DMODEL,
                                               ln_b + (l * 3 + 1) * DMODEL, x, nullptr);
        // ---- FFN ----
        gemm(x, w1h + (size_t)l * DFF * DMODEL, b1 + l * DFF, big, DMODEL, DFF, DFF, 1);
        gemm(big, w2h + (size_t)l * DMODEL * DFF, b2 + l * DMODEL, projo, DFF, DMODEL, DMODEL, 0);
        const bool last = (l == NLAYER - 1);
        k_add_ln<<<MTOT / 4, 256, 0, stream>>>(x, projo, ln_g + (l * 3 + 2) * DMODEL,
                                               ln_b + (l * 3 + 2) * DMODEL,
                                               last ? nullptr : x, last ? (float*)d_out : nullptr);
    }
    (void)in_sizes; (void)n_in; (void)out_size; (void)ws_size;
}